// Round 1
// baseline (1153.328 us; speedup 1.0000x reference)
//
#include <hip/hip_runtime.h>

#define N_NODES 16384
#define D_FEAT  128
#define HIDDEN  64

// ---------------------------------------------------------------------------
// Kernel 1: row sums. One wave (64 lanes) per row; each lane loads float2.
// ---------------------------------------------------------------------------
__global__ __launch_bounds__(256) void rowsum_kernel(const float* __restrict__ in,
                                                     float* __restrict__ out,
                                                     int nrows) {
    int wave = (blockIdx.x * blockDim.x + threadIdx.x) >> 6;
    int lane = threadIdx.x & 63;
    if (wave >= nrows) return;
    const float2 v = *reinterpret_cast<const float2*>(&in[wave * D_FEAT + lane * 2]);
    float sum = v.x + v.y;
    #pragma unroll
    for (int off = 32; off > 0; off >>= 1) sum += __shfl_down(sum, off, 64);
    if (lane == 0) out[wave] = sum;
}

// ---------------------------------------------------------------------------
// Kernel 2: pairwise fidelity + scalar-aggregate accumulation.
// Tile: 64 i-rows x 64 j-rows, block = 256 threads (16x16), each thread a
// 4x4 register block with STRIDED row mapping (row = t + 16*m) so LDS reads
// are <=2-way bank aliased (free).  LDS rows padded to 132 floats so row r
// starts at bank (4r mod 32).
// ---------------------------------------------------------------------------
#define TI 64
#define TJ 64
#define LDSPAD 132   // 132*4B = 528B per row, 16B-aligned, bank base = 4r mod 32

__global__ __launch_bounds__(256, 2) void pair_kernel(const float* __restrict__ x,
                                                      const float* __restrict__ s,
                                                      float* __restrict__ acc,
                                                      int jchunk) {
    __shared__ float As[TI][LDSPAD];
    __shared__ float Bs[TJ][LDSPAD];
    __shared__ float sj_lds[TJ];
    __shared__ float acc_lds[TI];

    const int i0 = blockIdx.x * TI;
    const int j0 = blockIdx.y * jchunk;
    const int tid = threadIdx.x;
    const int ty = tid >> 4;   // 0..15  (i sub-index)
    const int tx = tid & 15;   // 0..15  (j sub-index)

    if (tid < TI) acc_lds[tid] = 0.0f;

    // Stage A tile: 64 rows x 128 floats = 2048 float4s, 8 per thread.
    #pragma unroll
    for (int k = 0; k < 8; ++k) {
        int idx = tid + k * 256;          // 0..2047
        int r = idx >> 5;                 // row 0..63
        int c = (idx & 31) << 2;          // col 0,4,...,124
        *reinterpret_cast<float4*>(&As[r][c]) =
            *reinterpret_cast<const float4*>(&x[(size_t)(i0 + r) * D_FEAT + c]);
    }

    float local_acc[4] = {0.f, 0.f, 0.f, 0.f};

    const int ntiles = jchunk / TJ;
    for (int jt = 0; jt < ntiles; ++jt) {
        const int jbase = j0 + jt * TJ;

        __syncthreads();   // protect Bs/As from previous-iteration readers
        #pragma unroll
        for (int k = 0; k < 8; ++k) {
            int idx = tid + k * 256;
            int r = idx >> 5;
            int c = (idx & 31) << 2;
            *reinterpret_cast<float4*>(&Bs[r][c]) =
                *reinterpret_cast<const float4*>(&x[(size_t)(jbase + r) * D_FEAT + c]);
        }
        if (tid < TJ) sj_lds[tid] = s[jbase + tid];
        __syncthreads();

        float dot[4][4];
        #pragma unroll
        for (int m = 0; m < 4; ++m)
            #pragma unroll
            for (int n = 0; n < 4; ++n) dot[m][n] = 0.0f;

        #pragma unroll 4
        for (int d = 0; d < D_FEAT; d += 4) {
            float4 a[4], b[4];
            #pragma unroll
            for (int m = 0; m < 4; ++m)
                a[m] = *reinterpret_cast<const float4*>(&As[ty + 16 * m][d]);
            #pragma unroll
            for (int n = 0; n < 4; ++n)
                b[n] = *reinterpret_cast<const float4*>(&Bs[tx + 16 * n][d]);
            #pragma unroll
            for (int m = 0; m < 4; ++m)
                #pragma unroll
                for (int n = 0; n < 4; ++n) {
                    dot[m][n] = fmaf(a[m].x, b[n].x, dot[m][n]);
                    dot[m][n] = fmaf(a[m].y, b[n].y, dot[m][n]);
                    dot[m][n] = fmaf(a[m].z, b[n].z, dot[m][n]);
                    dot[m][n] = fmaf(a[m].w, b[n].w, dot[m][n]);
                }
        }

        // Threshold + accumulate neighbor row-sums.
        #pragma unroll
        for (int m = 0; m < 4; ++m) {
            const int gi = i0 + ty + 16 * m;
            float la = 0.0f;
            #pragma unroll
            for (int n = 0; n < 4; ++n) {
                const int lj = tx + 16 * n;
                const int gj = jbase + lj;
                const float dd = dot[m][n];
                if (dd * dd >= 0.85f && gi != gj) la += sj_lds[lj];
            }
            local_acc[m] += la;
        }
    }

    __syncthreads();
    #pragma unroll
    for (int m = 0; m < 4; ++m)
        atomicAdd(&acc_lds[ty + 16 * m], local_acc[m]);
    __syncthreads();
    if (tid < TI) atomicAdd(&acc[i0 + tid], acc_lds[tid]);
}

// ---------------------------------------------------------------------------
// Kernel 3: out[i][h] = (acc[i]/128) * wsum[h] + b[h]
// ---------------------------------------------------------------------------
__global__ __launch_bounds__(256) void out_kernel(const float* __restrict__ acc,
                                                  const float* __restrict__ wsum,
                                                  const float* __restrict__ b,
                                                  float* __restrict__ out) {
    int gid = blockIdx.x * blockDim.x + threadIdx.x;
    int i = gid >> 6;
    int h = gid & 63;
    float a = acc[i] * (1.0f / 128.0f);
    out[gid] = fmaf(a, wsum[h], b[h]);
}

// ---------------------------------------------------------------------------
extern "C" void kernel_launch(void* const* d_in, const int* in_sizes, int n_in,
                              void* d_out, int out_size, void* d_ws, size_t ws_size,
                              hipStream_t stream) {
    const float* x = (const float*)d_in[0];   // [16384,128]
    const float* W = (const float*)d_in[1];   // [64,128]
    const float* b = (const float*)d_in[2];   // [64]
    float* out = (float*)d_out;               // [16384,64]

    float* s    = (float*)d_ws;               // 16384
    float* acc  = s + N_NODES;                // 16384
    float* wsum = acc + N_NODES;              // 64

    // row sums of x and W
    rowsum_kernel<<<dim3((N_NODES * 64 + 255) / 256), dim3(256), 0, stream>>>(x, s, N_NODES);
    rowsum_kernel<<<dim3((HIDDEN * 64 + 255) / 256), dim3(256), 0, stream>>>(W, wsum, HIDDEN);

    // zero the accumulator (ws is poisoned 0xAA before every call)
    hipMemsetAsync(acc, 0, N_NODES * sizeof(float), stream);

    // pairwise kernel: 256 i-tiles x 2 j-chunks
    const int jchunk = N_NODES / 2;
    pair_kernel<<<dim3(N_NODES / TI, 2), dim3(256), 0, stream>>>(x, s, acc, jchunk);

    // output
    out_kernel<<<dim3(N_NODES * HIDDEN / 256), dim3(256), 0, stream>>>(acc, wsum, b, out);
}

// Round 3
// 327.206 us; speedup vs baseline: 3.5248x; 3.5248x over previous
//
#include <hip/hip_runtime.h>

#define N_NODES 16384
#define D_FEAT  128
#define HIDDEN  64
#define THRESH  0.85f
#define BAND    0.004f
#define LQCAP   512
#define NBLK    512          // 64 i-tiles x 8 j-chunks

typedef __attribute__((ext_vector_type(8))) short bf16x8;
typedef __attribute__((ext_vector_type(4))) float f32x4;

__device__ __forceinline__ unsigned short f32_to_bf16_rne(float f) {
    unsigned u = __float_as_uint(f);
    unsigned r = (u + 0x7FFFu + ((u >> 16) & 1u)) >> 16;
    return (unsigned short)r;
}

__device__ __forceinline__ void gl_lds16(const unsigned short* src, unsigned short* dst) {
    __builtin_amdgcn_global_load_lds(
        (const __attribute__((address_space(1))) unsigned int*)src,
        (__attribute__((address_space(3))) unsigned int*)dst, 16, 0, 0);
}

// ---------------------------------------------------------------------------
// Split x (f32) into bf16 hi/lo planes: x ~= hi + lo, each RNE-rounded.
// ---------------------------------------------------------------------------
__global__ __launch_bounds__(256) void convert_kernel(const float* __restrict__ x,
                                                      unsigned short* __restrict__ xhi,
                                                      unsigned short* __restrict__ xlo) {
    int t = blockIdx.x * 256 + threadIdx.x;      // one float4 per thread
    float4 v = ((const float4*)x)[t];
    float f[4] = {v.x, v.y, v.z, v.w};
    ushort4 ho, lo;
    unsigned short* hp = &ho.x;
    unsigned short* lp = &lo.x;
    #pragma unroll
    for (int k = 0; k < 4; ++k) {
        unsigned short h = f32_to_bf16_rne(f[k]);
        float hf = __uint_as_float(((unsigned)h) << 16);
        hp[k] = h;
        lp[k] = f32_to_bf16_rne(f[k] - hf);
    }
    ((ushort4*)xhi)[t] = ho;
    ((ushort4*)xlo)[t] = lo;
}

// ---------------------------------------------------------------------------
// Row sums (s_j = sum_d x[j][d]); also used for wsum of W.
// ---------------------------------------------------------------------------
__global__ __launch_bounds__(256) void rowsum_kernel(const float* __restrict__ in,
                                                     float* __restrict__ out,
                                                     int nrows) {
    int wave = (blockIdx.x * blockDim.x + threadIdx.x) >> 6;
    int lane = threadIdx.x & 63;
    if (wave >= nrows) return;
    const float2 v = *reinterpret_cast<const float2*>(&in[wave * D_FEAT + lane * 2]);
    float sum = v.x + v.y;
    #pragma unroll
    for (int off = 32; off > 0; off >>= 1) sum += __shfl_down(sum, off, 64);
    if (lane == 0) out[wave] = sum;
}

// ---------------------------------------------------------------------------
// MFMA pairwise kernel. Block = 4 waves x 64 i-rows = 256 rows; sweeps a
// 2048-row j-chunk in 64-row tiles.  dot = hi*hi + hi*lo + lo*hi (3 MFMAs),
// band pairs (|fid-0.85|<BAND) deferred to exact f32 fixup.
// LDS B-tile swizzle (G21 both-sides): granule G of row r stored at G^(r&7);
// read addr (kc*4+l4)^l7 with row&7==l7  -> max 2-way bank aliasing (free).
// ---------------------------------------------------------------------------
__global__ __launch_bounds__(256, 2) void pair_mfma(const unsigned short* __restrict__ xhi,
                                                    const unsigned short* __restrict__ xlo,
                                                    const float* __restrict__ s,
                                                    float* __restrict__ acc,
                                                    unsigned* __restrict__ gqueue,
                                                    int* __restrict__ gqcnt) {
    __shared__ unsigned short Bs[2][2][64][128];   // [buf][plane][row][col] 64 KB
    __shared__ unsigned lq[LQCAP];
    __shared__ int lqcnt, lqbase;

    const int tid  = threadIdx.x;
    const int lane = tid & 63;
    const int w    = tid >> 6;
    const int l15  = lane & 15, l4 = lane >> 4, l7 = lane & 7;

    // XCD-aware bijective swizzle: XCD k (bid%8) owns j-chunk k, all 64 i-tiles.
    const int bid = blockIdx.x;
    const int swz = (bid & 7) * 64 + (bid >> 3);
    const int it  = swz & 63;                 // i-tile (256 rows)
    const int jc  = swz >> 6;                 // j-chunk (2048 rows)
    const int i0  = it * 256 + w * 64;        // this wave's 64 rows
    const int jb0 = jc * 2048;

    // ---- persistent A fragments: 4 row-frags x 4 k-chunks x {hi,lo} = 128 VGPR ----
    bf16x8 ahi[4][4], alo[4][4];
    {
        const int abase = (i0 + l15) * D_FEAT + l4 * 8;
        #pragma unroll
        for (int rf = 0; rf < 4; ++rf)
            #pragma unroll
            for (int kc = 0; kc < 4; ++kc) {
                const int off = abase + rf * 16 * D_FEAT + kc * 32;
                ahi[rf][kc] = *(const bf16x8*)(xhi + off);
                alo[rf][kc] = *(const bf16x8*)(xlo + off);
            }
    }

    // staging source offset (elements): row=(tid>>4), granule XOR-swizzled by row&7
    const int base_off = (tid >> 4) * 128 + (((tid & 15) ^ ((tid >> 4) & 7)) * 8);
    unsigned short* const dst0 = &Bs[0][0][0][0] + w * 512;   // wave-uniform LDS dest

    // LDS read addressing: byte = buf*32768 + plane*16384 + cg*4096 + l15*256 + swzb[kc]
    const int rbyte = l15 * 256;
    int swzb[4];
    #pragma unroll
    for (int kc = 0; kc < 4; ++kc) swzb[kc] = (((kc * 4 + l4) ^ l7) * 16);

    // ---- prologue: stage tile 0 ----
    {
        const int jelem = jb0 * D_FEAT;
        const unsigned short* hsrc = xhi + jelem + base_off;
        const unsigned short* lsrc = xlo + jelem + base_off;
        #pragma unroll
        for (int q = 0; q < 4; ++q) gl_lds16(hsrc + q * 2048, dst0 + q * 2048);
        #pragma unroll
        for (int q = 0; q < 4; ++q) gl_lds16(lsrc + q * 2048, dst0 + 8192 + q * 2048);
    }
    if (tid == 0) lqcnt = 0;
    __syncthreads();

    float accf[4][4] = {{0.f}};
    const char* const BsBytes = (const char*)&Bs[0][0][0][0];

    for (int jt = 0; jt < 32; ++jt) {
        const int buf = jt & 1;
        const int jb = jb0 + jt * 64;

        // sv loads FIRST so their waitcnt doesn't drain the prefetch (vmcnt FIFO)
        float sv[4];
        #pragma unroll
        for (int cg = 0; cg < 4; ++cg) sv[cg] = s[jb + cg * 16 + l15];

        // issue next tile's staging (lands during compute; barrier drains)
        if (jt < 31) {
            const int jelem = (jb + 64) * D_FEAT;
            const unsigned short* hsrc = xhi + jelem + base_off;
            const unsigned short* lsrc = xlo + jelem + base_off;
            unsigned short* db = dst0 + (buf ^ 1) * 16384;
            #pragma unroll
            for (int q = 0; q < 4; ++q) gl_lds16(hsrc + q * 2048, db + q * 2048);
            #pragma unroll
            for (int q = 0; q < 4; ++q) gl_lds16(lsrc + q * 2048, db + 8192 + q * 2048);
        }

        const bool diag = (jb == i0);
        const char* bp = BsBytes + buf * 32768;

        #pragma unroll
        for (int cg = 0; cg < 4; ++cg) {
            f32x4 C[4];
            #pragma unroll
            for (int rf = 0; rf < 4; ++rf) C[rf] = (f32x4){0.f, 0.f, 0.f, 0.f};

            #pragma unroll
            for (int kc = 0; kc < 4; ++kc) {
                const bf16x8 bh = *(const bf16x8*)(bp + cg * 4096 + rbyte + swzb[kc]);
                const bf16x8 bl = *(const bf16x8*)(bp + 16384 + cg * 4096 + rbyte + swzb[kc]);
                #pragma unroll
                for (int rf = 0; rf < 4; ++rf) {
                    C[rf] = __builtin_amdgcn_mfma_f32_16x16x32_bf16(ahi[rf][kc], bh, C[rf], 0, 0, 0);
                    C[rf] = __builtin_amdgcn_mfma_f32_16x16x32_bf16(alo[rf][kc], bh, C[rf], 0, 0, 0);
                    C[rf] = __builtin_amdgcn_mfma_f32_16x16x32_bf16(ahi[rf][kc], bl, C[rf], 0, 0, 0);
                }
            }

            const int jcol = jb + cg * 16 + l15;
            const float svc = sv[cg];
            #pragma unroll
            for (int rf = 0; rf < 4; ++rf) {
                const int gib = i0 + rf * 16 + l4 * 4;
                #pragma unroll
                for (int r = 0; r < 4; ++r) {
                    const float d = C[rf][r];
                    const float tt = fmaf(d, d, -THRESH);
                    if (fabsf(tt) < BAND) {            // rare: defer to exact fixup
                        int p = atomicAdd(&lqcnt, 1);
                        if (p < LQCAP)
                            lq[p] = (((unsigned)(gib + r)) << 14) | (unsigned)jcol;
                    }
                    bool edge = (tt >= BAND);
                    if (diag) edge = edge && ((gib + r) != jcol);
                    accf[rf][r] += edge ? svc : 0.f;
                }
            }
        }
        __syncthreads();
    }

    // ---- flush band queue ----
    if (tid == 0) {
        int c = lqcnt; if (c > LQCAP) c = LQCAP;
        lqbase = atomicAdd(gqcnt, c);
        lqcnt = c;
    }
    __syncthreads();
    for (int p = tid; p < lqcnt; p += 256) gqueue[lqbase + p] = lq[p];

    // ---- reduce accf across the 16 lanes of each row-group, then atomicAdd ----
    #pragma unroll
    for (int rf = 0; rf < 4; ++rf)
        #pragma unroll
        for (int r = 0; r < 4; ++r) {
            float v = accf[rf][r];
            v += __shfl_xor(v, 1);
            v += __shfl_xor(v, 2);
            v += __shfl_xor(v, 4);
            v += __shfl_xor(v, 8);
            if (l15 == 0) atomicAdd(&acc[i0 + rf * 16 + l4 * 4 + r], v);
        }
}

// ---------------------------------------------------------------------------
// Exact f32 re-decision for band pairs: one pair per wave.
// ---------------------------------------------------------------------------
__global__ __launch_bounds__(256) void fixup_kernel(const unsigned* __restrict__ q,
                                                    const int* __restrict__ qcnt,
                                                    const float* __restrict__ x,
                                                    const float* __restrict__ s,
                                                    float* __restrict__ acc) {
    const int n = *qcnt;
    const int gw = (blockIdx.x * 256 + threadIdx.x) >> 6;
    const int lane = threadIdx.x & 63;
    const int nw = (gridDim.x * 256) >> 6;
    for (int p = gw; p < n; p += nw) {
        const unsigned e = q[p];
        const int i = (int)(e >> 14), j = (int)(e & 16383u);
        const float2 av = ((const float2*)(x + (size_t)i * D_FEAT))[lane];
        const float2 bv = ((const float2*)(x + (size_t)j * D_FEAT))[lane];
        float d = fmaf(av.y, bv.y, av.x * bv.x);
        #pragma unroll
        for (int off = 32; off > 0; off >>= 1) d += __shfl_xor(d, off);
        if (lane == 0) {
            const float tt = fmaf(d, d, -THRESH);
            if (tt >= 0.f) atomicAdd(&acc[i], s[j]);
        }
    }
}

// ---------------------------------------------------------------------------
// out[i][h] = (acc[i]/128) * wsum[h] + b[h]
// ---------------------------------------------------------------------------
__global__ __launch_bounds__(256) void out_kernel(const float* __restrict__ acc,
                                                  const float* __restrict__ wsum,
                                                  const float* __restrict__ b,
                                                  float* __restrict__ out) {
    int gid = blockIdx.x * blockDim.x + threadIdx.x;
    int i = gid >> 6;
    int h = gid & 63;
    float a = acc[i] * (1.0f / 128.0f);
    out[gid] = fmaf(a, wsum[h], b[h]);
}

// ---------------------------------------------------------------------------
extern "C" void kernel_launch(void* const* d_in, const int* in_sizes, int n_in,
                              void* d_out, int out_size, void* d_ws, size_t ws_size,
                              hipStream_t stream) {
    const float* x = (const float*)d_in[0];   // [16384,128]
    const float* W = (const float*)d_in[1];   // [64,128]
    const float* b = (const float*)d_in[2];   // [64]
    float* out = (float*)d_out;               // [16384,64]

    float*    s     = (float*)d_ws;                       // 16384
    float*    acc   = s + N_NODES;                        // 16384
    float*    wsum  = acc + N_NODES;                      // 64
    int*      qcnt  = (int*)(wsum + 64);
    unsigned* queue = (unsigned*)(qcnt + 64);             // NBLK*LQCAP = 1 MB
    unsigned short* xhi = (unsigned short*)((char*)d_ws + (2u << 20));
    unsigned short* xlo = (unsigned short*)((char*)d_ws + (6u << 20));

    convert_kernel<<<dim3(N_NODES * D_FEAT / 4 / 256), dim3(256), 0, stream>>>(x, xhi, xlo);
    rowsum_kernel<<<dim3((N_NODES * 64 + 255) / 256), dim3(256), 0, stream>>>(x, s, N_NODES);
    rowsum_kernel<<<dim3((HIDDEN * 64 + 255) / 256), dim3(256), 0, stream>>>(W, wsum, HIDDEN);
    hipMemsetAsync(acc, 0, N_NODES * sizeof(float), stream);
    hipMemsetAsync(qcnt, 0, sizeof(int), stream);

    pair_mfma<<<dim3(NBLK), dim3(256), 0, stream>>>(xhi, xlo, s, acc, queue, qcnt);
    fixup_kernel<<<dim3(256), dim3(256), 0, stream>>>(queue, qcnt, x, s, acc);
    out_kernel<<<dim3(N_NODES * HIDDEN / 256), dim3(256), 0, stream>>>(acc, wsum, b, out);
}

// Round 8
// 319.474 us; speedup vs baseline: 3.6101x; 1.0242x over previous
//
#include <hip/hip_runtime.h>

#define N_NODES 16384
#define D_FEAT  128
#define HIDDEN  64
#define THRESH  0.85f
#define BAND    0.004f
#define LQCAP   512
#define NBLK    512          // 64 i-tiles x 8 j-chunks
#define NT      64           // 32-row j-tiles per 2048-row chunk

typedef __attribute__((ext_vector_type(8))) short bf16x8;
typedef __attribute__((ext_vector_type(4))) float f32x4;

__device__ __forceinline__ unsigned short f32_to_bf16_rne(float f) {
    unsigned u = __float_as_uint(f);
    unsigned r = (u + 0x7FFFu + ((u >> 16) & 1u)) >> 16;
    return (unsigned short)r;
}

__device__ __forceinline__ void gl_lds16(const unsigned short* src, unsigned short* dst) {
    __builtin_amdgcn_global_load_lds(
        (const __attribute__((address_space(1))) unsigned int*)src,
        (__attribute__((address_space(3))) unsigned int*)dst, 16, 0, 0);
}

// ---------------------------------------------------------------------------
// Fused: bf16 hi/lo split of x  +  row sums s_i  +  zero acc/qcnt.
// 2048 blocks x 256 thr; block handles 8 rows (256 float4s, 1/thread).
// ---------------------------------------------------------------------------
__global__ __launch_bounds__(256) void convert_rowsum_kernel(const float* __restrict__ x,
                                                             unsigned short* __restrict__ xhi,
                                                             unsigned short* __restrict__ xlo,
                                                             float* __restrict__ s,
                                                             float* __restrict__ acc,
                                                             int* __restrict__ qcnt) {
    const int tid  = threadIdx.x;
    const int gidx = blockIdx.x * 256 + tid;         // float4 index
    float4 v = ((const float4*)x)[gidx];
    float f[4] = {v.x, v.y, v.z, v.w};
    ushort4 ho, lo;
    unsigned short* hp = &ho.x;
    unsigned short* lp = &lo.x;
    #pragma unroll
    for (int k = 0; k < 4; ++k) {
        unsigned short h = f32_to_bf16_rne(f[k]);
        float hf = __uint_as_float(((unsigned)h) << 16);
        hp[k] = h;
        lp[k] = f32_to_bf16_rne(f[k] - hf);
    }
    ((ushort4*)xhi)[gidx] = ho;
    ((ushort4*)xlo)[gidx] = lo;

    // segmented 32-lane reduce: lanes t..t+31 cover one 128-float row
    float sum = (v.x + v.y) + (v.z + v.w);
    #pragma unroll
    for (int off = 16; off > 0; off >>= 1) sum += __shfl_xor(sum, off);
    if ((tid & 31) == 0) s[blockIdx.x * 8 + (tid >> 5)] = sum;

    if (tid < 8) acc[blockIdx.x * 8 + tid] = 0.0f;
    if (gidx == 0) *qcnt = 0;
}

// ---------------------------------------------------------------------------
// Row sums for W (wsum), 64 rows.
// ---------------------------------------------------------------------------
__global__ __launch_bounds__(256) void rowsum_kernel(const float* __restrict__ in,
                                                     float* __restrict__ out,
                                                     int nrows) {
    int wave = (blockIdx.x * blockDim.x + threadIdx.x) >> 6;
    int lane = threadIdx.x & 63;
    if (wave >= nrows) return;
    const float2 v = *reinterpret_cast<const float2*>(&in[wave * D_FEAT + lane * 2]);
    float sum = v.x + v.y;
    #pragma unroll
    for (int off = 32; off > 0; off >>= 1) sum += __shfl_down(sum, off, 64);
    if (lane == 0) out[wave] = sum;
}

// ---------------------------------------------------------------------------
// MFMA pairwise kernel, T3/T4/T5: 32-row j-tiles, 3 LDS buffers, counted
// vmcnt(4) + raw s_barrier (never drained to 0 in-loop), setprio around MFMA.
// s[] chunk pre-staged to LDS so the VMEM FIFO holds ONLY staging loads:
// steady state = 8 outstanding, top-of-loop vmcnt(4) drains exactly tile t
// (in flight for 2 full iterations).  dot = hi*hi + hi*lo + lo*hi.
// Self-pair always counted; subtracted in out_kernel.
// ---------------------------------------------------------------------------
__global__ __launch_bounds__(256, 2) void pair_mfma(const unsigned short* __restrict__ xhi,
                                                    const unsigned short* __restrict__ xlo,
                                                    const float* __restrict__ s,
                                                    float* __restrict__ acc,
                                                    unsigned* __restrict__ gqueue,
                                                    int* __restrict__ gqcnt) {
    __shared__ unsigned short Bs[3][2][32][128];   // 3 x 16 KB
    __shared__ float s_lds[2048];                  // 8 KB: this chunk's s values
    __shared__ unsigned lq[LQCAP];
    __shared__ int lqcnt, lqbase;

    const int tid  = threadIdx.x;
    const int lane = tid & 63;
    const int w    = tid >> 6;
    const int l15  = lane & 15, l4 = lane >> 4, l7 = lane & 7;

    // XCD-aware bijective swizzle: XCD k (bid%8) owns j-chunk k, all 64 i-tiles.
    const int bid = blockIdx.x;
    const int swz = (bid & 7) * 64 + (bid >> 3);
    const int it  = swz & 63;                 // i-tile (256 rows)
    const int jc  = swz >> 6;                 // j-chunk (2048 rows)
    const int i0  = it * 256 + w * 64;        // this wave's 64 rows
    const int jb0 = jc * 2048;

    // ---- persistent A fragments: 4 row-frags x 4 k-chunks x {hi,lo} ----
    bf16x8 ahi[4][4], alo[4][4];
    {
        const int abase = (i0 + l15) * D_FEAT + l4 * 8;
        #pragma unroll
        for (int rf = 0; rf < 4; ++rf)
            #pragma unroll
            for (int kc = 0; kc < 4; ++kc) {
                const int off = abase + rf * 16 * D_FEAT + kc * 32;
                ahi[rf][kc] = *(const bf16x8*)(xhi + off);
                alo[rf][kc] = *(const bf16x8*)(xlo + off);
            }
    }

    // ---- stage s chunk to LDS (2 float4 per thread), zero lqcnt, seal ----
    {
        const float4* sp4 = (const float4*)(s + jb0);
        float4* sl4 = (float4*)s_lds;
        sl4[tid * 2]     = sp4[tid * 2];
        sl4[tid * 2 + 1] = sp4[tid * 2 + 1];
    }
    if (tid == 0) lqcnt = 0;
    __syncthreads();   // full drain once, BEFORE staging issues (keeps head start)

    // Staging geometry: 16 KB/tile = 16 x 1KB gl_lds; wave w issues ids w*4..+3.
    // id<8 -> hi plane, rows (id&7)*4..+3 ; id>=8 -> lo plane.
    // Source granule XOR-pre-swizzled by (row&7); LDS dest linear.
    int src_off[4]; int dst_off[4]; int plane_sel[4];
    #pragma unroll
    for (int q = 0; q < 4; ++q) {
        const int id = w * 4 + q;
        const int rowt = (id & 7) * 4 + l4;
        plane_sel[q] = id >> 3;
        src_off[q] = rowt * D_FEAT + ((l15 ^ (rowt & 7)) * 8);
        dst_off[q] = (id >> 3) * 4096 + (id & 7) * 512;   // elements
    }
    unsigned short* const BsE = &Bs[0][0][0][0];

    // ---- prologue: stage tiles 0,1 into buffers 0,1 (8 outstanding) ----
    #pragma unroll
    for (int tt = 0; tt < 2; ++tt) {
        const int jelem = (jb0 + tt * 32) * D_FEAT;
        #pragma unroll
        for (int q = 0; q < 4; ++q) {
            const unsigned short* sp = (plane_sel[q] ? xlo : xhi) + jelem + src_off[q];
            gl_lds16(sp, BsE + tt * 8192 + dst_off[q]);
        }
    }

    float accf[4][4] = {{0.f}};
    const char* const BsBytes = (const char*)BsE;
    const int rbyte = l15 * 256;
    int swzb[4];
    #pragma unroll
    for (int kc = 0; kc < 4; ++kc) swzb[kc] = (((kc * 4 + l4) ^ l7) * 16);

    int bufc = 0, bufs = 2;    // compute buf = t%3, stage buf = (t+2)%3
    for (int t = 0; t < NT; ++t) {
        // T4: counted wait — tile t landed; tiles t+1,(t+2 partial) stay in flight
        asm volatile("s_waitcnt vmcnt(4)" ::: "memory");
        __builtin_amdgcn_s_barrier();

        // stage tile t+2 (wrap &63: dead-but-in-bounds on last 2 iters)
        {
            const int jelem = (jb0 + ((t + 2) & 63) * 32) * D_FEAT;
            unsigned short* db = BsE + bufs * 8192;
            #pragma unroll
            for (int q = 0; q < 4; ++q) {
                const unsigned short* sp = (plane_sel[q] ? xlo : xhi) + jelem + src_off[q];
                gl_lds16(sp, db + dst_off[q]);
            }
        }

        const int jb = jb0 + t * 32;
        const char* bp = BsBytes + bufc * 16384;

        #pragma unroll
        for (int cg = 0; cg < 2; ++cg) {
            f32x4 C[4];
            #pragma unroll
            for (int rf = 0; rf < 4; ++rf) C[rf] = (f32x4){0.f, 0.f, 0.f, 0.f};

            __builtin_amdgcn_s_setprio(1);
            #pragma unroll
            for (int kc = 0; kc < 4; ++kc) {
                const bf16x8 bh = *(const bf16x8*)(bp + cg * 4096 + rbyte + swzb[kc]);
                const bf16x8 bl = *(const bf16x8*)(bp + 8192 + cg * 4096 + rbyte + swzb[kc]);
                #pragma unroll
                for (int rf = 0; rf < 4; ++rf) {
                    C[rf] = __builtin_amdgcn_mfma_f32_16x16x32_bf16(ahi[rf][kc], bh, C[rf], 0, 0, 0);
                    C[rf] = __builtin_amdgcn_mfma_f32_16x16x32_bf16(alo[rf][kc], bh, C[rf], 0, 0, 0);
                    C[rf] = __builtin_amdgcn_mfma_f32_16x16x32_bf16(ahi[rf][kc], bl, C[rf], 0, 0, 0);
                }
            }
            __builtin_amdgcn_s_setprio(0);

            const int jcol = jb + cg * 16 + l15;
            const float svc = s_lds[t * 32 + cg * 16 + l15];   // broadcast read, free
            #pragma unroll
            for (int rf = 0; rf < 4; ++rf) {
                const int gib = i0 + rf * 16 + l4 * 4;
                #pragma unroll
                for (int r = 0; r < 4; ++r) {
                    const float d = C[rf][r];
                    const float tt = fmaf(d, d, -THRESH);
                    if (fabsf(tt) < BAND) {            // rare: defer to exact fixup
                        int p = atomicAdd(&lqcnt, 1);
                        if (p < LQCAP)
                            lq[p] = (((unsigned)(gib + r)) << 14) | (unsigned)jcol;
                    }
                    accf[rf][r] += (tt >= BAND) ? svc : 0.f;
                }
            }
        }

        bufc = (bufc == 2) ? 0 : bufc + 1;
        bufs = (bufs == 2) ? 0 : bufs + 1;
    }

    __syncthreads();   // post-loop: full drain OK (once)

    // ---- flush band queue ----
    if (tid == 0) {
        int c = lqcnt; if (c > LQCAP) c = LQCAP;
        lqbase = atomicAdd(gqcnt, c);
        lqcnt = c;
    }
    __syncthreads();
    for (int p = tid; p < lqcnt; p += 256) gqueue[lqbase + p] = lq[p];

    // ---- reduce accf across the 16 lanes of each row-group, then atomicAdd ----
    #pragma unroll
    for (int rf = 0; rf < 4; ++rf)
        #pragma unroll
        for (int r = 0; r < 4; ++r) {
            float v = accf[rf][r];
            v += __shfl_xor(v, 1);
            v += __shfl_xor(v, 2);
            v += __shfl_xor(v, 4);
            v += __shfl_xor(v, 8);
            if (l15 == 0) atomicAdd(&acc[i0 + rf * 16 + l4 * 4 + r], v);
        }
}

// ---------------------------------------------------------------------------
// Exact f32 re-decision for band pairs: one pair per wave.
// ---------------------------------------------------------------------------
__global__ __launch_bounds__(256) void fixup_kernel(const unsigned* __restrict__ q,
                                                    const int* __restrict__ qcnt,
                                                    const float* __restrict__ x,
                                                    const float* __restrict__ s,
                                                    float* __restrict__ acc) {
    const int n = *qcnt;
    const int gw = (blockIdx.x * 256 + threadIdx.x) >> 6;
    const int lane = threadIdx.x & 63;
    const int nw = (gridDim.x * 256) >> 6;
    for (int p = gw; p < n; p += nw) {
        const unsigned e = q[p];
        const int i = (int)(e >> 14), j = (int)(e & 16383u);
        const float2 av = ((const float2*)(x + (size_t)i * D_FEAT))[lane];
        const float2 bv = ((const float2*)(x + (size_t)j * D_FEAT))[lane];
        float d = fmaf(av.y, bv.y, av.x * bv.x);
        #pragma unroll
        for (int off = 32; off > 0; off >>= 1) d += __shfl_xor(d, off);
        if (lane == 0) {
            const float tt = fmaf(d, d, -THRESH);
            if (tt >= 0.f) atomicAdd(&acc[i], s[j]);
        }
    }
}

// ---------------------------------------------------------------------------
// out[i][h] = ((acc[i] - s[i])/128) * wsum[h] + b[h]
// (self-pair was always counted as an edge in pair_mfma; removed here)
// ---------------------------------------------------------------------------
__global__ __launch_bounds__(256) void out_kernel(const float* __restrict__ acc,
                                                  const float* __restrict__ s,
                                                  const float* __restrict__ wsum,
                                                  const float* __restrict__ b,
                                                  float* __restrict__ out) {
    int gid = blockIdx.x * blockDim.x + threadIdx.x;
    int i = gid >> 6;
    int h = gid & 63;
    float a = (acc[i] - s[i]) * (1.0f / 128.0f);
    out[gid] = fmaf(a, wsum[h], b[h]);
}

// ---------------------------------------------------------------------------
extern "C" void kernel_launch(void* const* d_in, const int* in_sizes, int n_in,
                              void* d_out, int out_size, void* d_ws, size_t ws_size,
                              hipStream_t stream) {
    const float* x = (const float*)d_in[0];   // [16384,128]
    const float* W = (const float*)d_in[1];   // [64,128]
    const float* b = (const float*)d_in[2];   // [64]
    float* out = (float*)d_out;               // [16384,64]

    float*    s     = (float*)d_ws;                       // 16384
    float*    acc   = s + N_NODES;                        // 16384
    float*    wsum  = acc + N_NODES;                      // 64
    int*      qcnt  = (int*)(wsum + 64);
    unsigned* queue = (unsigned*)(qcnt + 64);             // NBLK*LQCAP = 1 MB
    unsigned short* xhi = (unsigned short*)((char*)d_ws + (2u << 20));
    unsigned short* xlo = (unsigned short*)((char*)d_ws + (6u << 20));

    convert_rowsum_kernel<<<dim3(N_NODES / 8), dim3(256), 0, stream>>>(x, xhi, xlo, s, acc, qcnt);
    rowsum_kernel<<<dim3((HIDDEN * 64 + 255) / 256), dim3(256), 0, stream>>>(W, wsum, HIDDEN);

    pair_mfma<<<dim3(NBLK), dim3(256), 0, stream>>>(xhi, xlo, s, acc, queue, qcnt);
    fixup_kernel<<<dim3(256), dim3(256), 0, stream>>>(queue, qcnt, x, s, acc);
    out_kernel<<<dim3(N_NODES * HIDDEN / 256), dim3(256), 0, stream>>>(acc, s, wsum, b, out);
}